// Round 1
// baseline (3283.567 us; speedup 1.0000x reference)
//
#include <hip/hip_runtime.h>
#include <math.h>

#define N_ATOMS 50000
#define N_PAIRS 1600000
#define NF 128
#define NRBF 20

__device__ __forceinline__ float sspf(float x) {
    // softplus(x) - log(2), numerically stable
    return fmaxf(x, 0.0f) + log1pf(__expf(-fabsf(x))) - 0.69314718055994530942f;
}

// out[m, half*64+c] = postop(A[m,:128] @ W[:128, half*64+c] + bias[half*64+c])
// block=256, grid=(nblk, 2). Tile: 32 rows x 64 cols, 2x4 per thread.
template<bool SSP_OUT>
__global__ __launch_bounds__(256) void gemm128_kernel(
    const float* __restrict__ A, const float* __restrict__ W,
    const float* __restrict__ bias, float* __restrict__ out, int M)
{
    __shared__ __align__(16) float Wh[128][64];   // 32 KB: W half, [k][c]
    __shared__ __align__(16) float AT[128][34];   // 17 KB: A tile transposed, +2 pad
    const int t = threadIdx.x;
    const int half = blockIdx.y;

    // stage W half (8192 floats = 2048 float4, 8 per thread)
    #pragma unroll
    for (int i = 0; i < 8; ++i) {
        int idx = t + 256 * i;
        int k = idx >> 4, c4 = idx & 15;
        *(float4*)&Wh[k][c4 * 4] = *(const float4*)&W[k * 128 + half * 64 + c4 * 4];
    }
    const int c0 = (t & 15) * 4;
    const int r0t = (t >> 4) * 2;
    const float4 bv = *(const float4*)&bias[half * 64 + c0];

    const int ntiles = (M + 31) >> 5;
    for (int tile = blockIdx.x; tile < ntiles; tile += gridDim.x) {
        const int row0 = tile << 5;
        __syncthreads();   // covers Wh on iter 0; protects AT from prev readers
        #pragma unroll
        for (int i = 0; i < 16; ++i) {
            int idx = t + 256 * i;
            int r = idx >> 7, k = idx & 127;
            int gr = row0 + r;
            AT[k][r] = (gr < M) ? A[gr * 128 + k] : 0.0f;  // coalesced read, 2-way LDS write
        }
        __syncthreads();
        float acc[2][4] = {{0.f,0.f,0.f,0.f},{0.f,0.f,0.f,0.f}};
        #pragma unroll 8
        for (int k = 0; k < 128; ++k) {
            float2 a = *(const float2*)&AT[k][r0t];
            float4 w = *(const float4*)&Wh[k][c0];
            acc[0][0] = fmaf(a.x, w.x, acc[0][0]);
            acc[0][1] = fmaf(a.x, w.y, acc[0][1]);
            acc[0][2] = fmaf(a.x, w.z, acc[0][2]);
            acc[0][3] = fmaf(a.x, w.w, acc[0][3]);
            acc[1][0] = fmaf(a.y, w.x, acc[1][0]);
            acc[1][1] = fmaf(a.y, w.y, acc[1][1]);
            acc[1][2] = fmaf(a.y, w.z, acc[1][2]);
            acc[1][3] = fmaf(a.y, w.w, acc[1][3]);
        }
        #pragma unroll
        for (int q = 0; q < 2; ++q) {
            int gr = row0 + r0t + q;
            if (gr < M) {
                float4 o;
                o.x = acc[q][0] + bv.x; o.y = acc[q][1] + bv.y;
                o.z = acc[q][2] + bv.z; o.w = acc[q][3] + bv.w;
                if (SSP_OUT) { o.x = sspf(o.x); o.y = sspf(o.y); o.z = sspf(o.z); o.w = sspf(o.w); }
                *(float4*)&out[gr * 128 + half * 64 + c0] = o;
            }
        }
    }
}

// Fused edge kernel: Wij = (ssp(f_ij@Wf1+bf1)@Wf2+bf2)*rcut; agg[idx_i] += h[idx_j]*Wij
// block=256, grid=(nblk, 2) — gridDim.y splits the 128 filters into two 64-halves.
__global__ __launch_bounds__(256) void edge_kernel(
    const float* __restrict__ f_ij, const float* __restrict__ rcut,
    const float* __restrict__ Wf1, const float* __restrict__ bf1,
    const float* __restrict__ Wf2, const float* __restrict__ bf2,
    const int* __restrict__ idx_i, const int* __restrict__ idx_j,
    const float* __restrict__ h, float* __restrict__ agg)
{
    __shared__ __align__(16) float Wh[128][64];   // 32 KB Wf2 half
    __shared__ __align__(16) float sT[128][34];   // 17 KB ssp output, transposed, +2 pad
    __shared__ __align__(16) float fE[32][20];    // 2.5 KB rbf tile (20 floats = 16B-mult rows)
    __shared__ int ii[32];
    __shared__ int jj[32];
    __shared__ float rc[32];
    const int t = threadIdx.x;
    const int half = blockIdx.y;

    #pragma unroll
    for (int i = 0; i < 8; ++i) {
        int idx = t + 256 * i;
        int k = idx >> 4, c4 = idx & 15;
        *(float4*)&Wh[k][c4 * 4] = *(const float4*)&Wf2[k * 128 + half * 64 + c4 * 4];
    }
    // mm1 mapping: thread owns k-column kcol, handles 16 edges (ehalf)
    const int kcol = t & 127;
    const int ehalf = t >> 7;
    float wf1r[NRBF];
    #pragma unroll
    for (int r = 0; r < NRBF; ++r) wf1r[r] = Wf1[r * 128 + kcol];
    const float bf1r = bf1[kcol];
    // mm2 mapping: 4 cols x 2 edges per thread
    const int c0 = (t & 15) * 4;
    const int e0t = (t >> 4) * 2;
    const float4 b2 = *(const float4*)&bf2[half * 64 + c0];

    const int ntiles = N_PAIRS / 32;   // 50000, exact
    for (int tile = blockIdx.x; tile < ntiles; tile += gridDim.x) {
        const int e0 = tile * 32;
        __syncthreads();
        // stage f_ij tile (640 floats = 160 float4) + indices
        if (t < 160) ((float4*)&fE[0][0])[t] = ((const float4*)(f_ij + e0 * 20))[t];
        if (t >= 192 && t < 224) {
            int e = t - 192;
            ii[e] = idx_i[e0 + e]; jj[e] = idx_j[e0 + e]; rc[e] = rcut[e0 + e];
        }
        __syncthreads();
        // mm1 + ssp: sT[k][e] = ssp(f_ij[e]@Wf1[:,k] + bf1[k])
        #pragma unroll 2
        for (int e = 0; e < 16; ++e) {
            int el = ehalf * 16 + e;
            const float4* f4 = (const float4*)&fE[el][0];   // broadcast reads
            float4 fa = f4[0], fb = f4[1], fc = f4[2], fd = f4[3], fg = f4[4];
            float xv = bf1r;
            xv = fmaf(fa.x, wf1r[0], xv);  xv = fmaf(fa.y, wf1r[1], xv);
            xv = fmaf(fa.z, wf1r[2], xv);  xv = fmaf(fa.w, wf1r[3], xv);
            xv = fmaf(fb.x, wf1r[4], xv);  xv = fmaf(fb.y, wf1r[5], xv);
            xv = fmaf(fb.z, wf1r[6], xv);  xv = fmaf(fb.w, wf1r[7], xv);
            xv = fmaf(fc.x, wf1r[8], xv);  xv = fmaf(fc.y, wf1r[9], xv);
            xv = fmaf(fc.z, wf1r[10], xv); xv = fmaf(fc.w, wf1r[11], xv);
            xv = fmaf(fd.x, wf1r[12], xv); xv = fmaf(fd.y, wf1r[13], xv);
            xv = fmaf(fd.z, wf1r[14], xv); xv = fmaf(fd.w, wf1r[15], xv);
            xv = fmaf(fg.x, wf1r[16], xv); xv = fmaf(fg.y, wf1r[17], xv);
            xv = fmaf(fg.z, wf1r[18], xv); xv = fmaf(fg.w, wf1r[19], xv);
            sT[kcol][el] = sspf(xv);   // 2-way bank alias (free)
        }
        __syncthreads();
        // mm2: Wij[e][c] = sT[:, e] . Wh[:, c]
        float acc[2][4] = {{0.f,0.f,0.f,0.f},{0.f,0.f,0.f,0.f}};
        #pragma unroll 8
        for (int k = 0; k < 128; ++k) {
            float2 s = *(const float2*)&sT[k][e0t];
            float4 w = *(const float4*)&Wh[k][c0];
            acc[0][0] = fmaf(s.x, w.x, acc[0][0]);
            acc[0][1] = fmaf(s.x, w.y, acc[0][1]);
            acc[0][2] = fmaf(s.x, w.z, acc[0][2]);
            acc[0][3] = fmaf(s.x, w.w, acc[0][3]);
            acc[1][0] = fmaf(s.y, w.x, acc[1][0]);
            acc[1][1] = fmaf(s.y, w.y, acc[1][1]);
            acc[1][2] = fmaf(s.y, w.z, acc[1][2]);
            acc[1][3] = fmaf(s.y, w.w, acc[1][3]);
        }
        // epilogue: bias, rcut scale, gather h[idx_j], scatter-add agg[idx_i]
        #pragma unroll
        for (int q = 0; q < 2; ++q) {
            int el = e0t + q;
            int ia = ii[el], ja = jj[el];
            float rv = rc[el];
            float4 hv = *(const float4*)&h[ja * 128 + half * 64 + c0];
            float v0 = (acc[q][0] + b2.x) * rv;
            float v1 = (acc[q][1] + b2.y) * rv;
            float v2 = (acc[q][2] + b2.z) * rv;
            float v3 = (acc[q][3] + b2.w) * rv;
            float* ap = &agg[ia * 128 + half * 64 + c0];
            atomicAdd(ap + 0, hv.x * v0);
            atomicAdd(ap + 1, hv.y * v1);
            atomicAdd(ap + 2, hv.z * v2);
            atomicAdd(ap + 3, hv.w * v3);
        }
    }
}

extern "C" void kernel_launch(void* const* d_in, const int* in_sizes, int n_in,
                              void* d_out, int out_size, void* d_ws, size_t ws_size,
                              hipStream_t stream) {
    const float* x     = (const float*)d_in[0];
    const float* f_ij  = (const float*)d_in[1];
    const float* rcutp = (const float*)d_in[2];
    const float* W_in  = (const float*)d_in[3];
    const float* b_in  = (const float*)d_in[4];
    const float* Wf1   = (const float*)d_in[5];
    const float* bf1   = (const float*)d_in[6];
    const float* Wf2   = (const float*)d_in[7];
    const float* bf2   = (const float*)d_in[8];
    const float* Wo1   = (const float*)d_in[9];
    const float* bo1   = (const float*)d_in[10];
    const float* Wo2   = (const float*)d_in[11];
    const float* bo2   = (const float*)d_in[12];
    const int* idx_i   = (const int*)d_in[13];
    const int* idx_j   = (const int*)d_in[14];
    float* out = (float*)d_out;

    float* h   = (float*)d_ws;                       // 25.6 MB
    float* agg = h + (size_t)N_ATOMS * NF;           // 25.6 MB
    float* tmp = h;                                  // alias: h dead after edge kernel

    hipMemsetAsync(agg, 0, (size_t)N_ATOMS * NF * sizeof(float), stream);
    gemm128_kernel<false><<<dim3(512, 2), 256, 0, stream>>>(x, W_in, b_in, h, N_ATOMS);
    edge_kernel<<<dim3(768, 2), 256, 0, stream>>>(f_ij, rcutp, Wf1, bf1, Wf2, bf2,
                                                  idx_i, idx_j, h, agg);
    gemm128_kernel<true ><<<dim3(512, 2), 256, 0, stream>>>(agg, Wo1, bo1, tmp, N_ATOMS);
    gemm128_kernel<false><<<dim3(512, 2), 256, 0, stream>>>(tmp, Wo2, bo2, out, N_ATOMS);
}

// Round 2
// 1419.541 us; speedup vs baseline: 2.3131x; 2.3131x over previous
//
#include <hip/hip_runtime.h>
#include <math.h>

#define N_ATOMS 50000
#define N_PAIRS 1600000
#define NF 128
#define NRBF 20
#define NTILES (N_PAIRS / 64)   // 25000 tiles of 64 edges

typedef _Float16 half8 __attribute__((ext_vector_type(8)));
typedef float floatx4 __attribute__((ext_vector_type(4)));

__device__ __forceinline__ float sspf(float x) {
    // softplus(x) - log(2), numerically stable
    return fmaxf(x, 0.0f) + log1pf(__expf(-fabsf(x))) - 0.69314718055994530942f;
}

// out[m, half*64+c] = postop(A[m,:128] @ W[:128, half*64+c] + bias[half*64+c])
template<bool SSP_OUT>
__global__ __launch_bounds__(256) void gemm128_kernel(
    const float* __restrict__ A, const float* __restrict__ W,
    const float* __restrict__ bias, float* __restrict__ out, int M)
{
    __shared__ __align__(16) float Wh[128][64];
    __shared__ __align__(16) float AT[128][34];
    const int t = threadIdx.x;
    const int half = blockIdx.y;

    #pragma unroll
    for (int i = 0; i < 8; ++i) {
        int idx = t + 256 * i;
        int k = idx >> 4, c4 = idx & 15;
        *(float4*)&Wh[k][c4 * 4] = *(const float4*)&W[k * 128 + half * 64 + c4 * 4];
    }
    const int c0 = (t & 15) * 4;
    const int r0t = (t >> 4) * 2;
    const float4 bv = *(const float4*)&bias[half * 64 + c0];

    const int ntiles = (M + 31) >> 5;
    for (int tile = blockIdx.x; tile < ntiles; tile += gridDim.x) {
        const int row0 = tile << 5;
        __syncthreads();
        #pragma unroll
        for (int i = 0; i < 16; ++i) {
            int idx = t + 256 * i;
            int r = idx >> 7, k = idx & 127;
            int gr = row0 + r;
            AT[k][r] = (gr < M) ? A[gr * 128 + k] : 0.0f;
        }
        __syncthreads();
        float acc[2][4] = {{0.f,0.f,0.f,0.f},{0.f,0.f,0.f,0.f}};
        #pragma unroll 8
        for (int k = 0; k < 128; ++k) {
            float2 a = *(const float2*)&AT[k][r0t];
            float4 w = *(const float4*)&Wh[k][c0];
            acc[0][0] = fmaf(a.x, w.x, acc[0][0]);
            acc[0][1] = fmaf(a.x, w.y, acc[0][1]);
            acc[0][2] = fmaf(a.x, w.z, acc[0][2]);
            acc[0][3] = fmaf(a.x, w.w, acc[0][3]);
            acc[1][0] = fmaf(a.y, w.x, acc[1][0]);
            acc[1][1] = fmaf(a.y, w.y, acc[1][1]);
            acc[1][2] = fmaf(a.y, w.z, acc[1][2]);
            acc[1][3] = fmaf(a.y, w.w, acc[1][3]);
        }
        #pragma unroll
        for (int q = 0; q < 2; ++q) {
            int gr = row0 + r0t + q;
            if (gr < M) {
                float4 o;
                o.x = acc[q][0] + bv.x; o.y = acc[q][1] + bv.y;
                o.z = acc[q][2] + bv.z; o.w = acc[q][3] + bv.w;
                if (SSP_OUT) { o.x = sspf(o.x); o.y = sspf(o.y); o.z = sspf(o.z); o.w = sspf(o.w); }
                *(float4*)&out[gr * 128 + half * 64 + c0] = o;
            }
        }
    }
}

// MFMA edge kernel. 64-edge tiles, 4 waves x 16 edges, fp16 MFMA 16x16x32.
// mm1: s = ssp(f_ij @ Wf1 + bf1)   [64 x 128], A=f (from global), B=Wf1 (regs)
// mm2: Wij = s @ Wf2 + bf2, *rcut  [64 x 128], A=s (LDS round-trip), B=Wf2 (LDS)
// epilogue: agg[idx_i] += h[idx_j] * Wij   (atomics)
__global__ __launch_bounds__(256) void edge_kernel(
    const float* __restrict__ f_ij, const float* __restrict__ rcut,
    const float* __restrict__ Wf1, const float* __restrict__ bf1,
    const float* __restrict__ Wf2, const float* __restrict__ bf2,
    const int* __restrict__ idx_i, const int* __restrict__ idx_j,
    const float* __restrict__ h, float* __restrict__ agg)
{
    __shared__ __align__(16) _Float16 sW2[128][136];  // Wf2^T: [c][k], 34816 B
    __shared__ __align__(16) _Float16 sS[64][136];    // s tile: [e][k], 17408 B

    const int t = threadIdx.x;
    const int w = t >> 6;         // wave 0..3
    const int lane = t & 63;
    const int m = lane & 15;      // MFMA row/col-within-group
    const int q = lane >> 4;      // quad 0..3

    // ---- one-time init ----
    for (int i = t; i < 128 * 128; i += 256) {
        int k = i >> 7, c = i & 127;               // coalesced read of Wf2[k][c]
        sW2[c][k] = (_Float16)Wf2[i];
    }
    half8 bW1[8];                                   // mm1 B-frags: B[k=q*8+j][n=g*16+m]
    #pragma unroll
    for (int g = 0; g < 8; ++g) {
        #pragma unroll
        for (int j = 0; j < 8; ++j) {
            int k = q * 8 + j;
            bW1[g][j] = (k < NRBF) ? (_Float16)Wf1[k * 128 + g * 16 + m] : (_Float16)0.0f;
        }
    }
    float bf1r[8], bf2r[8];
    #pragma unroll
    for (int g = 0; g < 8; ++g) { bf1r[g] = bf1[g * 16 + m]; bf2r[g] = bf2[g * 16 + m]; }
    __syncthreads();   // sW2 ready; no barriers needed after this

    const floatx4 zero4 = {0.f, 0.f, 0.f, 0.f};

    for (int tile = blockIdx.x; tile < NTILES; tile += gridDim.x) {
        const int e0 = tile * 64 + w * 16;

        // A1 frag: f_ij[e0+m][q*8 .. q*8+7], zero-padded past rbf=20
        half8 a1 = {};
        {
            const float* fb = f_ij + (size_t)(e0 + m) * NRBF + q * 8;
            if (q < 2) {
                float4 u0 = *(const float4*)fb;
                float4 u1 = *(const float4*)(fb + 4);
                a1[0] = (_Float16)u0.x; a1[1] = (_Float16)u0.y;
                a1[2] = (_Float16)u0.z; a1[3] = (_Float16)u0.w;
                a1[4] = (_Float16)u1.x; a1[5] = (_Float16)u1.y;
                a1[6] = (_Float16)u1.z; a1[7] = (_Float16)u1.w;
            } else if (q == 2) {
                float4 u0 = *(const float4*)fb;
                a1[0] = (_Float16)u0.x; a1[1] = (_Float16)u0.y;
                a1[2] = (_Float16)u0.z; a1[3] = (_Float16)u0.w;
            }
        }

        // mm1: 8 MFMAs cover 16 edges x 128 filters
        floatx4 c1[8];
        #pragma unroll
        for (int g = 0; g < 8; ++g)
            c1[g] = __builtin_amdgcn_mfma_f32_16x16x32_f16(a1, bW1[g], zero4, 0, 0, 0);

        // per-edge meta for the 4 C-rows this lane owns (rows q*4+r)
        int iia[4], jja[4]; float rca[4];
        #pragma unroll
        for (int r = 0; r < 4; ++r) {
            int er = e0 + q * 4 + r;
            iia[r] = idx_i[er]; jja[r] = idx_j[er]; rca[r] = rcut[er];
        }

        // ssp + cast, write s to LDS in row-major [e][k]
        #pragma unroll
        for (int g = 0; g < 8; ++g) {
            #pragma unroll
            for (int r = 0; r < 4; ++r) {
                float v = sspf(c1[g][r] + bf1r[g]);
                sS[w * 16 + q * 4 + r][g * 16 + m] = (_Float16)v;
            }
        }

        // mm2 A-frags: s[w*16+m][s32*32 + q*8 ..+7]  (same-wave rows; lgkmcnt orders)
        half8 a2[4];
        #pragma unroll
        for (int s = 0; s < 4; ++s)
            a2[s] = *(const half8*)&sS[w * 16 + m][s * 32 + q * 8];

        // mm2: 8 col-groups x 4 K-steps
        floatx4 acc2[8];
        #pragma unroll
        for (int g = 0; g < 8; ++g) {
            floatx4 a = zero4;
            #pragma unroll
            for (int s = 0; s < 4; ++s) {
                half8 b = *(const half8*)&sW2[g * 16 + m][s * 32 + q * 8];
                a = __builtin_amdgcn_mfma_f32_16x16x32_f16(a2[s], b, a, 0, 0, 0);
            }
            acc2[g] = a;
        }

        // epilogue: bias, rcut, gather h[idx_j], scatter-add agg[idx_i]
        #pragma unroll
        for (int r = 0; r < 4; ++r) {
            const float* hrow = h + (size_t)jja[r] * NF;
            float* arow = agg + (size_t)iia[r] * NF;
            float rv = rca[r];
            #pragma unroll
            for (int g = 0; g < 8; ++g) {
                int c = g * 16 + m;
                float wij = (acc2[g][r] + bf2r[g]) * rv;
                atomicAdd(&arow[c], hrow[c] * wij);
            }
        }
    }
}

extern "C" void kernel_launch(void* const* d_in, const int* in_sizes, int n_in,
                              void* d_out, int out_size, void* d_ws, size_t ws_size,
                              hipStream_t stream) {
    const float* x     = (const float*)d_in[0];
    const float* f_ij  = (const float*)d_in[1];
    const float* rcutp = (const float*)d_in[2];
    const float* W_in  = (const float*)d_in[3];
    const float* b_in  = (const float*)d_in[4];
    const float* Wf1   = (const float*)d_in[5];
    const float* bf1   = (const float*)d_in[6];
    const float* Wf2   = (const float*)d_in[7];
    const float* bf2   = (const float*)d_in[8];
    const float* Wo1   = (const float*)d_in[9];
    const float* bo1   = (const float*)d_in[10];
    const float* Wo2   = (const float*)d_in[11];
    const float* bo2   = (const float*)d_in[12];
    const int* idx_i   = (const int*)d_in[13];
    const int* idx_j   = (const int*)d_in[14];
    float* out = (float*)d_out;

    float* h   = (float*)d_ws;                       // 25.6 MB
    float* agg = h + (size_t)N_ATOMS * NF;           // 25.6 MB
    float* tmp = h;                                  // h dead after edge kernel

    hipMemsetAsync(agg, 0, (size_t)N_ATOMS * NF * sizeof(float), stream);
    gemm128_kernel<false><<<dim3(512, 2), 256, 0, stream>>>(x, W_in, b_in, h, N_ATOMS);
    edge_kernel<<<dim3(1024), 256, 0, stream>>>(f_ij, rcutp, Wf1, bf1, Wf2, bf2,
                                                idx_i, idx_j, h, agg);
    gemm128_kernel<true ><<<dim3(512, 2), 256, 0, stream>>>(agg, Wo1, bo1, tmp, N_ATOMS);
    gemm128_kernel<false><<<dim3(512, 2), 256, 0, stream>>>(tmp, Wo2, bo2, out, N_ATOMS);
}

// Round 3
// 1030.261 us; speedup vs baseline: 3.1871x; 1.3778x over previous
//
#include <hip/hip_runtime.h>
#include <math.h>

#define N_ATOMS 50000
#define N_PAIRS 1600000
#define NF 128
#define NRBF 20

typedef _Float16 half8 __attribute__((ext_vector_type(8)));
typedef float floatx4 __attribute__((ext_vector_type(4)));

__device__ __forceinline__ float sspf(float x) {
    // softplus(x) - log(2) via HW exp2/log2; abs err ~1e-6
    float t = __expf(-fabsf(x));
    return fmaxf(x, 0.0f) + __logf(1.0f + t) - 0.69314718055994530942f;
}

// out[M x 128] = postop(A[M x 128] @ W[128 x 128] + bias), fp16 MFMA, fp32 A in/out.
// 256 threads = 4 waves; 64-row tiles; wave w owns rows w*16..w*16+15.
template<bool SSP_OUT>
__global__ __launch_bounds__(256) void gemm_mfma_kernel(
    const float* __restrict__ A, const float* __restrict__ W,
    const float* __restrict__ bias, float* __restrict__ out, int M)
{
    __shared__ __align__(16) _Float16 sW[128][136];   // [c][k], 34816 B -> 4 blocks/CU
    const int t = threadIdx.x;
    const int w = t >> 6;
    const int lane = t & 63;
    const int m = lane & 15;
    const int q = lane >> 4;

    for (int i = t; i < 128 * 128; i += 256) {
        int k = i >> 7, c = i & 127;
        sW[c][k] = (_Float16)W[i];            // coalesced global read
    }
    float bv[8];
    #pragma unroll
    for (int g = 0; g < 8; ++g) bv[g] = bias[g * 16 + m];
    __syncthreads();   // sW ready; loop is barrier-free

    const floatx4 zero4 = {0.f, 0.f, 0.f, 0.f};
    const int ntiles = (M + 63) >> 6;
    for (int tile = blockIdx.x; tile < ntiles; tile += gridDim.x) {
        const int arow = tile * 64 + w * 16 + m;
        half8 a[4];
        if (arow < M) {
            const float* ap = A + (size_t)arow * 128;
            #pragma unroll
            for (int s = 0; s < 4; ++s) {
                float4 u0 = *(const float4*)(ap + s * 32 + q * 8);
                float4 u1 = *(const float4*)(ap + s * 32 + q * 8 + 4);
                a[s][0] = (_Float16)u0.x; a[s][1] = (_Float16)u0.y;
                a[s][2] = (_Float16)u0.z; a[s][3] = (_Float16)u0.w;
                a[s][4] = (_Float16)u1.x; a[s][5] = (_Float16)u1.y;
                a[s][6] = (_Float16)u1.z; a[s][7] = (_Float16)u1.w;
            }
        } else {
            #pragma unroll
            for (int s = 0; s < 4; ++s) a[s] = (half8){};
        }
        floatx4 acc[8];
        #pragma unroll
        for (int g = 0; g < 8; ++g) {
            floatx4 c = zero4;
            #pragma unroll
            for (int s = 0; s < 4; ++s) {
                half8 b = *(const half8*)&sW[g * 16 + m][s * 32 + q * 8];  // 2-way alias: free
                c = __builtin_amdgcn_mfma_f32_16x16x32_f16(a[s], b, c, 0, 0, 0);
            }
            acc[g] = c;
        }
        #pragma unroll
        for (int r = 0; r < 4; ++r) {
            const int grow = tile * 64 + w * 16 + q * 4 + r;
            if (grow < M) {
                float* op = out + (size_t)grow * 128;
                #pragma unroll
                for (int g = 0; g < 8; ++g) {
                    float v = acc[g][r] + bv[g];
                    if (SSP_OUT) v = sspf(v);
                    op[g * 16 + m] = v;
                }
            }
        }
    }
}

// Edge kernel v3: 512 threads = 8 waves, 64-edge tiles.
// Wave (p = w&3, hf = w>>2): edges p*16..p*16+15, filter half hf (64 cols).
// mm1 half (4 MFMA) -> ssp -> sS; barrier; mm2 (full-K A-frags, 16 MFMA); epilogue; barrier.
__global__ __launch_bounds__(512) void edge_kernel(
    const float* __restrict__ f_ij, const float* __restrict__ rcut,
    const float* __restrict__ Wf1, const float* __restrict__ bf1,
    const float* __restrict__ Wf2, const float* __restrict__ bf2,
    const int* __restrict__ idx_i, const int* __restrict__ idx_j,
    const float* __restrict__ h, float* __restrict__ agg)
{
    __shared__ __align__(16) _Float16 sW2[128][136];  // Wf2^T [c][k], 34816 B
    __shared__ __align__(16) _Float16 sS[64][136];    // s tile [e][k], 17408 B

    const int t = threadIdx.x;
    const int w = t >> 6;
    const int lane = t & 63;
    const int m = lane & 15;
    const int q = lane >> 4;
    const int p  = w & 3;     // edge sub-tile
    const int hf = w >> 2;    // filter half

    for (int i = t; i < 128 * 128; i += 512) {
        int k = i >> 7, c = i & 127;
        sW2[c][k] = (_Float16)Wf2[i];
    }
    half8 bW1[4];
    #pragma unroll
    for (int g = 0; g < 4; ++g) {
        int col = hf * 64 + g * 16 + m;
        #pragma unroll
        for (int j = 0; j < 8; ++j) {
            int k = q * 8 + j;
            bW1[g][j] = (k < NRBF) ? (_Float16)Wf1[k * 128 + col] : (_Float16)0.0f;
        }
    }
    float bf1r[4], bf2r[4];
    #pragma unroll
    for (int g = 0; g < 4; ++g) {
        int col = hf * 64 + g * 16 + m;
        bf1r[g] = bf1[col]; bf2r[g] = bf2[col];
    }
    __syncthreads();   // sW2 ready

    const floatx4 zero4 = {0.f, 0.f, 0.f, 0.f};
    for (int tile = blockIdx.x; tile < N_PAIRS / 64; tile += gridDim.x) {
        const int e0 = tile * 64 + p * 16;

        // A1 frag: f_ij[e0+m][q*8..q*8+7], zero-padded past rbf=20
        half8 a1 = {};
        {
            const float* fb = f_ij + (size_t)(e0 + m) * NRBF + q * 8;
            if (q < 2) {
                float4 u0 = *(const float4*)fb;
                float4 u1 = *(const float4*)(fb + 4);
                a1[0] = (_Float16)u0.x; a1[1] = (_Float16)u0.y;
                a1[2] = (_Float16)u0.z; a1[3] = (_Float16)u0.w;
                a1[4] = (_Float16)u1.x; a1[5] = (_Float16)u1.y;
                a1[6] = (_Float16)u1.z; a1[7] = (_Float16)u1.w;
            } else if (q == 2) {
                float4 u0 = *(const float4*)fb;
                a1[0] = (_Float16)u0.x; a1[1] = (_Float16)u0.y;
                a1[2] = (_Float16)u0.z; a1[3] = (_Float16)u0.w;
            }
        }

        // mm1: 4 MFMAs for this wave's filter half
        floatx4 c1[4];
        #pragma unroll
        for (int g = 0; g < 4; ++g)
            c1[g] = __builtin_amdgcn_mfma_f32_16x16x32_f16(a1, bW1[g], zero4, 0, 0, 0);

        // per-edge meta (C rows q*4+r)
        int iia[4], jja[4]; float rca[4];
        #pragma unroll
        for (int r = 0; r < 4; ++r) {
            int er = e0 + q * 4 + r;
            iia[r] = idx_i[er]; jja[r] = idx_j[er]; rca[r] = rcut[er];
        }

        // ssp + fp16 store to sS (this wave's 64 cols)
        #pragma unroll
        for (int g = 0; g < 4; ++g) {
            #pragma unroll
            for (int r = 0; r < 4; ++r) {
                float v = sspf(c1[g][r] + bf1r[g]);
                sS[p * 16 + q * 4 + r][hf * 64 + g * 16 + m] = (_Float16)v;
            }
        }
        __syncthreads();   // full sS rows ready (both hf halves)

        // mm2 A-frags: full-K rows of this wave's edge sub-tile
        half8 a2[4];
        #pragma unroll
        for (int s = 0; s < 4; ++s)
            a2[s] = *(const half8*)&sS[p * 16 + m][s * 32 + q * 8];

        // mm2: 4 col-groups (this half) x 4 K-steps
        floatx4 acc2[4];
        #pragma unroll
        for (int g = 0; g < 4; ++g) {
            floatx4 c = zero4;
            #pragma unroll
            for (int s = 0; s < 4; ++s) {
                half8 b = *(const half8*)&sW2[hf * 64 + g * 16 + m][s * 32 + q * 8];
                c = __builtin_amdgcn_mfma_f32_16x16x32_f16(a2[s], b, c, 0, 0, 0);
            }
            acc2[g] = c;
        }

        // epilogue: bias, rcut, gather h[idx_j], scatter-add agg[idx_i]
        #pragma unroll
        for (int r = 0; r < 4; ++r) {
            const float* hrow = h + (size_t)jja[r] * NF;
            float* arow = agg + (size_t)iia[r] * NF;
            float rv = rca[r];
            #pragma unroll
            for (int g = 0; g < 4; ++g) {
                int c = hf * 64 + g * 16 + m;
                float wij = (acc2[g][r] + bf2r[g]) * rv;
                atomicAdd(&arow[c], hrow[c] * wij);
            }
        }
        __syncthreads();   // WAR: protect sS before next tile's writes
    }
}

extern "C" void kernel_launch(void* const* d_in, const int* in_sizes, int n_in,
                              void* d_out, int out_size, void* d_ws, size_t ws_size,
                              hipStream_t stream) {
    const float* x     = (const float*)d_in[0];
    const float* f_ij  = (const float*)d_in[1];
    const float* rcutp = (const float*)d_in[2];
    const float* W_in  = (const float*)d_in[3];
    const float* b_in  = (const float*)d_in[4];
    const float* Wf1   = (const float*)d_in[5];
    const float* bf1   = (const float*)d_in[6];
    const float* Wf2   = (const float*)d_in[7];
    const float* bf2   = (const float*)d_in[8];
    const float* Wo1   = (const float*)d_in[9];
    const float* bo1   = (const float*)d_in[10];
    const float* Wo2   = (const float*)d_in[11];
    const float* bo2   = (const float*)d_in[12];
    const int* idx_i   = (const int*)d_in[13];
    const int* idx_j   = (const int*)d_in[14];
    float* out = (float*)d_out;

    float* h   = (float*)d_ws;                       // 25.6 MB
    float* agg = h + (size_t)N_ATOMS * NF;           // 25.6 MB
    float* tmp = h;                                  // h dead after edge kernel

    hipMemsetAsync(agg, 0, (size_t)N_ATOMS * NF * sizeof(float), stream);
    gemm_mfma_kernel<false><<<dim3(768), 256, 0, stream>>>(x, W_in, b_in, h, N_ATOMS);
    edge_kernel<<<dim3(768), 512, 0, stream>>>(f_ij, rcutp, Wf1, bf1, Wf2, bf2,
                                               idx_i, idx_j, h, agg);
    gemm_mfma_kernel<true ><<<dim3(768), 256, 0, stream>>>(agg, Wo1, bo1, tmp, N_ATOMS);
    gemm_mfma_kernel<false><<<dim3(768), 256, 0, stream>>>(tmp, Wo2, bo2, out, N_ATOMS);
}

// Round 4
// 916.157 us; speedup vs baseline: 3.5841x; 1.1245x over previous
//
#include <hip/hip_runtime.h>
#include <math.h>

#define N_ATOMS 50000
#define N_PAIRS 1600000
#define NF 128
#define NRBF 20
#define NTILES (N_PAIRS / 64)   // 25000

typedef _Float16 half8 __attribute__((ext_vector_type(8)));
typedef float floatx4 __attribute__((ext_vector_type(4)));

__device__ __forceinline__ float sspf(float x) {
    float t = __expf(-fabsf(x));
    return fmaxf(x, 0.0f) + __logf(1.0f + t) - 0.69314718055994530942f;
}

// Swizzled LDS layout for a [128 rows x 128 fp16] matrix (256 B rows).
// 16B group k8 of row r lives at XOR'd position (k8 ^ (r & 15)).
// b128 reads with row==lane-m land 16 distinct groups -> 2-way (free).
__device__ __forceinline__ int swz16(int row, int k8) {
    return row * 256 + ((k8 ^ (row & 15)) << 4);
}

// Stage fp32 W[128][128] (row-major [k][c]) into LDS as fp16 transposed [c][k], swizzled.
template<int NTHR>
__device__ __forceinline__ void stage_w(const float* __restrict__ W, char* dst, int t) {
    for (int i = t; i < 128 * 128; i += NTHR) {
        int c = i & 127, k = i >> 7;                     // coalesced in c
        *(_Float16*)(dst + swz16(c, k >> 3) + ((k & 7) << 1)) = (_Float16)W[k * 128 + c];
    }
}

// Generic 128x128 MFMA gemm: out = postop(A @ W + bias). 256 thr = 4 waves, 64-row tiles,
// wave-private full-K rows -> no in-loop barriers. Optionally zero-fills zbuf (fused memset).
template<typename TIN, typename TOUT, bool SSP_OUT, bool ZERO>
__global__ __launch_bounds__(256) void gemm_mfma_kernel(
    const TIN* __restrict__ A, const float* __restrict__ W,
    const float* __restrict__ bias, TOUT* __restrict__ out, int M,
    float* __restrict__ zbuf, int zcount4)
{
    __shared__ char sW[32768];
    const int t = threadIdx.x;
    const int w = t >> 6, lane = t & 63, m = lane & 15, q = lane >> 4;

    if (ZERO) {
        float4 z = {0.f, 0.f, 0.f, 0.f};
        for (int i = blockIdx.x * 256 + t; i < zcount4; i += gridDim.x * 256)
            ((float4*)zbuf)[i] = z;
    }
    stage_w<256>(W, sW, t);
    float bv[8];
    #pragma unroll
    for (int g = 0; g < 8; ++g) bv[g] = bias[g * 16 + m];
    __syncthreads();

    const floatx4 zero4 = {0.f, 0.f, 0.f, 0.f};
    const int ntiles = (M + 63) >> 6;
    for (int tile = blockIdx.x; tile < ntiles; tile += gridDim.x) {
        const int arow = tile * 64 + w * 16 + m;
        half8 a[4];
        if (arow < M) {
            const TIN* ap = A + (size_t)arow * 128;
            #pragma unroll
            for (int s = 0; s < 4; ++s) {
                if (sizeof(TIN) == 2) {
                    a[s] = *(const half8*)(ap + s * 32 + q * 8);
                } else {
                    float4 u0 = *(const float4*)((const float*)ap + s * 32 + q * 8);
                    float4 u1 = *(const float4*)((const float*)ap + s * 32 + q * 8 + 4);
                    a[s][0] = (_Float16)u0.x; a[s][1] = (_Float16)u0.y;
                    a[s][2] = (_Float16)u0.z; a[s][3] = (_Float16)u0.w;
                    a[s][4] = (_Float16)u1.x; a[s][5] = (_Float16)u1.y;
                    a[s][6] = (_Float16)u1.z; a[s][7] = (_Float16)u1.w;
                }
            }
        } else {
            #pragma unroll
            for (int s = 0; s < 4; ++s) a[s] = (half8){};
        }
        floatx4 acc[8];
        #pragma unroll
        for (int g = 0; g < 8; ++g) {
            floatx4 c = zero4;
            #pragma unroll
            for (int s = 0; s < 4; ++s) {
                half8 b = *(const half8*)(sW + swz16(g * 16 + m, 4 * s + q));
                c = __builtin_amdgcn_mfma_f32_16x16x32_f16(a[s], b, c, 0, 0, 0);
            }
            acc[g] = c;
        }
        #pragma unroll
        for (int r = 0; r < 4; ++r) {
            const int grow = tile * 64 + w * 16 + q * 4 + r;
            if (grow < M) {
                TOUT* op = out + (size_t)grow * 128;
                #pragma unroll
                for (int g = 0; g < 8; ++g) {
                    float v = acc[g][r] + bv[g];
                    if (SSP_OUT) v = sspf(v);
                    op[g * 16 + m] = (TOUT)v;
                }
            }
        }
    }
}

// Edge kernel v4: 256 thr = 4 waves, 64-edge tiles, wave owns 16 edges FULL-K.
// Zero in-loop barriers (wave-private sS slab). Prefetch next tile f/idx_j; h-gathers
// issued at tile top and consumed after mm2; atomics fire-and-forget across tiles.
__global__ __launch_bounds__(256) void edge_kernel(
    const float* __restrict__ f_ij, const float* __restrict__ rcut,
    const float* __restrict__ Wf1, const float* __restrict__ bf1,
    const float* __restrict__ Wf2, const float* __restrict__ bf2,
    const int* __restrict__ idx_i, const int* __restrict__ idx_j,
    const _Float16* __restrict__ h, float* __restrict__ agg)
{
    __shared__ char sW2[32768];
    __shared__ char sS[4][4096];   // wave-private 16-row slabs
    const int t = threadIdx.x;
    const int w = t >> 6, lane = t & 63, m = lane & 15, q = lane >> 4;

    stage_w<256>(Wf2, sW2, t);
    half8 bW1[8];
    #pragma unroll
    for (int g = 0; g < 8; ++g) {
        #pragma unroll
        for (int j = 0; j < 8; ++j) {
            int k = q * 8 + j;
            bW1[g][j] = (k < NRBF) ? (_Float16)Wf1[k * 128 + g * 16 + m] : (_Float16)0.0f;
        }
    }
    float bf1r[8], bf2r[8];
    #pragma unroll
    for (int g = 0; g < 8; ++g) { bf1r[g] = bf1[g * 16 + m]; bf2r[g] = bf2[g * 16 + m]; }
    __syncthreads();   // sW2 ready; no barriers after this

    char* mySS = sS[w];
    const floatx4 zero4 = {0.f, 0.f, 0.f, 0.f};
    const float4 fz = {0.f, 0.f, 0.f, 0.f};
    const int stride = gridDim.x;

    // --- prefetch tile 0 ---
    float4 f0 = fz, f1 = fz; int4 jj4;
    {
        int e0 = blockIdx.x * 64 + w * 16;
        const float* fb = f_ij + (size_t)(e0 + m) * NRBF + q * 8;
        if (q < 2)      { f0 = *(const float4*)fb; f1 = *(const float4*)(fb + 4); }
        else if (q == 2){ f0 = *(const float4*)fb; }
        jj4 = *(const int4*)&idx_j[e0 + q * 4];
    }

    for (int tile = blockIdx.x; tile < NTILES; tile += stride) {
        const int e0 = tile * 64 + w * 16;
        int ntile = tile + stride; if (ntile >= NTILES) ntile = tile;

        // 1) issue h-gathers for current tile (rows from prefetched jj4)
        int jj[4] = {jj4.x, jj4.y, jj4.z, jj4.w};
        _Float16 hv[4][8];
        #pragma unroll
        for (int r = 0; r < 4; ++r) {
            const _Float16* hp = h + (size_t)jj[r] * 128;
            #pragma unroll
            for (int g = 0; g < 8; ++g) hv[r][g] = hp[g * 16 + m];
        }
        // 2) issue epilogue meta
        int4 ii4 = *(const int4*)&idx_i[e0 + q * 4];
        float4 rc4 = *(const float4*)&rcut[e0 + q * 4];

        // 3) mm1 from prefetched f
        half8 a1;
        a1[0]=(_Float16)f0.x; a1[1]=(_Float16)f0.y; a1[2]=(_Float16)f0.z; a1[3]=(_Float16)f0.w;
        a1[4]=(_Float16)f1.x; a1[5]=(_Float16)f1.y; a1[6]=(_Float16)f1.z; a1[7]=(_Float16)f1.w;
        floatx4 c1[8];
        #pragma unroll
        for (int g = 0; g < 8; ++g)
            c1[g] = __builtin_amdgcn_mfma_f32_16x16x32_f16(a1, bW1[g], zero4, 0, 0, 0);

        // 4) prefetch next tile's f/idx_j
        float4 nf0 = fz, nf1 = fz; int4 njj4;
        {
            int ne0 = ntile * 64 + w * 16;
            const float* fb = f_ij + (size_t)(ne0 + m) * NRBF + q * 8;
            if (q < 2)      { nf0 = *(const float4*)fb; nf1 = *(const float4*)(fb + 4); }
            else if (q == 2){ nf0 = *(const float4*)fb; }
            njj4 = *(const int4*)&idx_j[ne0 + q * 4];
        }

        // 5) ssp + write s to private slab (fp16, swizzled)
        #pragma unroll
        for (int g = 0; g < 8; ++g) {
            #pragma unroll
            for (int r = 0; r < 4; ++r) {
                float v = sspf(c1[g][r] + bf1r[g]);
                *(_Float16*)(mySS + swz16(q * 4 + r, 2 * g + (m >> 3)) + ((m & 7) << 1)) =
                    (_Float16)v;
            }
        }

        // 6) read back A-frags (same-wave rows; lgkmcnt orders, no barrier)
        half8 a2[4];
        #pragma unroll
        for (int s = 0; s < 4; ++s)
            a2[s] = *(const half8*)(mySS + swz16(m, 4 * s + q));

        // 7) mm2
        floatx4 acc[8];
        #pragma unroll
        for (int g = 0; g < 8; ++g) {
            floatx4 c = zero4;
            #pragma unroll
            for (int s = 0; s < 4; ++s) {
                half8 b = *(const half8*)(sW2 + swz16(g * 16 + m, 4 * s + q));
                c = __builtin_amdgcn_mfma_f32_16x16x32_f16(a2[s], b, c, 0, 0, 0);
            }
            acc[g] = c;
        }

        // 8) epilogue: consume gathers, scatter-add (fire-and-forget atomics)
        int ii[4] = {ii4.x, ii4.y, ii4.z, ii4.w};
        float rc[4] = {rc4.x, rc4.y, rc4.z, rc4.w};
        #pragma unroll
        for (int r = 0; r < 4; ++r) {
            float* arow = agg + (size_t)ii[r] * 128;
            #pragma unroll
            for (int g = 0; g < 8; ++g) {
                float wij = (acc[g][r] + bf2r[g]) * rc[r];
                atomicAdd(&arow[g * 16 + m], (float)hv[r][g] * wij);
            }
        }

        f0 = nf0; f1 = nf1; jj4 = njj4;
    }
}

extern "C" void kernel_launch(void* const* d_in, const int* in_sizes, int n_in,
                              void* d_out, int out_size, void* d_ws, size_t ws_size,
                              hipStream_t stream) {
    const float* x     = (const float*)d_in[0];
    const float* f_ij  = (const float*)d_in[1];
    const float* rcutp = (const float*)d_in[2];
    const float* W_in  = (const float*)d_in[3];
    const float* b_in  = (const float*)d_in[4];
    const float* Wf1   = (const float*)d_in[5];
    const float* bf1   = (const float*)d_in[6];
    const float* Wf2   = (const float*)d_in[7];
    const float* bf2   = (const float*)d_in[8];
    const float* Wo1   = (const float*)d_in[9];
    const float* bo1   = (const float*)d_in[10];
    const float* Wo2   = (const float*)d_in[11];
    const float* bo2   = (const float*)d_in[12];
    const int* idx_i   = (const int*)d_in[13];
    const int* idx_j   = (const int*)d_in[14];
    float* out = (float*)d_out;

    float*     agg = (float*)d_ws;                                   // 25.6 MB fp32
    _Float16*  h   = (_Float16*)((char*)d_ws + (size_t)N_ATOMS * NF * 4);  // 12.8 MB fp16
    _Float16*  tmp = h;                                              // h dead after edge

    const int zc4 = N_ATOMS * NF / 4;
    // h = x@W_in+b (fp16 out), fused agg zero-fill
    gemm_mfma_kernel<float, _Float16, false, true>
        <<<dim3(782), 256, 0, stream>>>(x, W_in, b_in, h, N_ATOMS, agg, zc4);
    edge_kernel<<<dim3(768), 256, 0, stream>>>(f_ij, rcutp, Wf1, bf1, Wf2, bf2,
                                               idx_i, idx_j, h, agg);
    // tmp = ssp(agg@Wo1+bo1) (fp16), out = tmp@Wo2+bo2 (fp32)
    gemm_mfma_kernel<float, _Float16, true, false>
        <<<dim3(782), 256, 0, stream>>>(agg, Wo1, bo1, tmp, N_ATOMS, nullptr, 0);
    gemm_mfma_kernel<_Float16, float, false, false>
        <<<dim3(782), 256, 0, stream>>>(tmp, Wo2, bo2, out, N_ATOMS, nullptr, 0);
}